// Round 4
// baseline (933.298 us; speedup 1.0000x reference)
//
#include <hip/hip_runtime.h>
#include <cmath>

#define L_DIM 2048
#define C_CH  16
#define B_SZ  2
#define N_G   4
#define C_PG  4
#define K_SZ  11
#define PADK  5

#define TY 64
#define TX 32
#define HY (TY + K_SZ - 1)   /* 74 */
#define NCHUNK 6             /* 8-wide x-chunks: px = x0-8 .. x0+39 */
#define PITCHW 52            /* u32 pitch: 2-way bank alias only; 16B-aligned rows */

typedef _Float16 f16;
typedef __attribute__((ext_vector_type(2))) _Float16 half2v;

union U32H2 { unsigned u; half2v h; unsigned short s[2]; };

struct alignas(8) H4 { f16 x, y, z, w; };

// hardware packed dot product: acc += w.lo*p.lo + w.hi*p.hi (f32 accumulate)
__device__ __forceinline__ float dot2a(unsigned w, unsigned p, float acc) {
  asm("v_dot2_f32_f16 %0, %1, %2, %0" : "+v"(acc) : "v"(w), "v"(p));
  return acc;
}

// ---- pack weights as (f16 lo=ci even, hi=ci odd) u32 into probs plane-0 ----
// row r = g*2+cp (8 rows), each row holds [co][ky][12] = 528 u32 at f16 col 32.
// Hole is provably untouched: softmax row y stores only cols <= y+3 <= 10 for
// y<8; conv staging reads row y only at cols <= y <= 7 for these rows.
__global__ void pack_w_k(const float* __restrict__ weight, f16* __restrict__ probs) {
  const int t = threadIdx.x;
  for (int idx = t; idx < 8 * 528; idx += 256) {
    const int row  = idx / 528;
    const int rem  = idx - row * 528;
    const int co   = rem / 132;
    const int rem2 = rem - co * 132;
    const int ky   = rem2 / 12;
    const int kx   = rem2 - ky * 12;
    const int g = row >> 1, cp = row & 1;
    unsigned pk = 0;
    if (kx < 11) {
      const int c = g * 4 + co;
      const float* wb = weight + (((size_t)c * C_PG + cp * 2) * K_SZ + ky) * K_SZ + kx;
      U32H2 u;
      u.h = half2v{(f16)wb[0], (f16)wb[K_SZ * K_SZ]};
      pk = u.u;
    }
    unsigned* dst = reinterpret_cast<unsigned*>(probs + (size_t)row * L_DIM + 32);
    dst[rem] = pk;
  }
}

// ---------------- causal softmax: one wave per row ----------------
__global__ __launch_bounds__(256) void softmax_rows_k(
    const float* __restrict__ scores, f16* __restrict__ probs) {
  const int wid  = (blockIdx.x << 2) + (threadIdx.x >> 6);
  const int lane = threadIdx.x & 63;
  const int y    = wid & (L_DIM - 1);
  const float* srow = scores + (size_t)wid * L_DIM;

  float v[32];
#pragma unroll
  for (int j = 0; j < 8; ++j) {
    const int x = j * 256 + lane * 4;
    float4 f = make_float4(-INFINITY, -INFINITY, -INFINITY, -INFINITY);
    if (x <= y)
      f = *reinterpret_cast<const float4*>(srow + x);
    v[4*j+0] = (x + 0 <= y) ? f.x : -INFINITY;
    v[4*j+1] = (x + 1 <= y) ? f.y : -INFINITY;
    v[4*j+2] = (x + 2 <= y) ? f.z : -INFINITY;
    v[4*j+3] = (x + 3 <= y) ? f.w : -INFINITY;
  }
  float m = v[0];
#pragma unroll
  for (int i = 1; i < 32; ++i) m = fmaxf(m, v[i]);
#pragma unroll
  for (int off = 32; off >= 1; off >>= 1) m = fmaxf(m, __shfl_xor(m, off, 64));

  float s = 0.f;
#pragma unroll
  for (int i = 0; i < 32; ++i) { v[i] = __expf(v[i] - m); s += v[i]; }
#pragma unroll
  for (int off = 32; off >= 1; off >>= 1) s += __shfl_xor(s, off, 64);
  const float inv = 1.0f / s;

  f16* prow = probs + (size_t)wid * L_DIM;
#pragma unroll
  for (int j = 0; j < 8; ++j) {
    const int x = j * 256 + lane * 4;
    if (x > y) continue;
    H4 h;
    h.x = (f16)(v[4*j+0] * inv);
    h.y = (f16)(v[4*j+1] * inv);
    h.z = (f16)(v[4*j+2] * inv);
    h.w = (f16)(v[4*j+3] * inv);
    *reinterpret_cast<H4*>(prow + x) = h;
  }
}

// ---------------- grouped 11x11 conv: v_dot2 + SGPR weights ----------------
// block: 256 threads -> 64(y) x 32(x) tile x 4 output channels (one group)
// thread: 1 row (tyg = tid>>2), 8 consecutive x (txg = tid&3), 4 co -> 32 acc
__global__ __launch_bounds__(256) void conv_k(
    const f16* __restrict__ probs, const float* __restrict__ bias,
    float* __restrict__ out) {
  const int x0  = blockIdx.x * TX;
  const int y0  = blockIdx.y * TY;
  const int b   = blockIdx.z >> 2;
  const int g   = blockIdx.z & 3;
  const int tid = threadIdx.x;
  const int txg = tid & 3;
  const int tyg = tid >> 2;       // 0..63
  const int xb  = x0 + 8 * txg;   // thread x base
  const int gy  = y0 + tyg;       // thread output row

  // tile entirely above the diagonal -> pure zeros
  if (x0 > y0 + TY - 1) {
    const float4 z4 = make_float4(0.f, 0.f, 0.f, 0.f);
#pragma unroll
    for (int co = 0; co < 4; ++co) {
      float* op = out + ((size_t)(b * C_CH + g * 4 + co) * L_DIM + gy) * L_DIM + xb;
      *reinterpret_cast<float4*>(op) = z4;
      *reinterpret_cast<float4*>(op + 4) = z4;
    }
    return;
  }

  __shared__ unsigned tile[2][HY * PITCHW];   // [pair][y][x] packed ci-pairs

  // ---- stage all 4 input channels via 16B loads + v_perm interleave ----
  {
    const size_t plane = (size_t)L_DIM * L_DIM;
    const f16* base = probs + ((size_t)(b * C_CH) + g * C_PG) * plane;
    for (int u = tid; u < HY * NCHUNK; u += 256) {
      const int row = u / NCHUNK;
      const int c   = u - row * NCHUNK;
      const int py  = y0 + row - PADK;
      const int px0 = x0 - 8 + 8 * c;     // 8-aligned -> OOB is chunk-uniform
      unsigned t0[8] = {0,0,0,0,0,0,0,0};
      unsigned t1[8] = {0,0,0,0,0,0,0,0};
      if (py >= 0 && py < L_DIM && px0 >= 0 && px0 < L_DIM && px0 <= py) {
        const size_t o = (size_t)py * L_DIM + px0;   // even -> 16B aligned
        uint4 A0 = *reinterpret_cast<const uint4*>(base + o);
        uint4 A1 = *reinterpret_cast<const uint4*>(base + plane + o);
        uint4 A2 = *reinterpret_cast<const uint4*>(base + 2 * plane + o);
        uint4 A3 = *reinterpret_cast<const uint4*>(base + 3 * plane + o);
        const unsigned* a0 = reinterpret_cast<const unsigned*>(&A0);
        const unsigned* a1 = reinterpret_cast<const unsigned*>(&A1);
        const unsigned* a2 = reinterpret_cast<const unsigned*>(&A2);
        const unsigned* a3 = reinterpret_cast<const unsigned*>(&A3);
#pragma unroll
        for (int e = 0; e < 4; ++e) {
          t0[2*e]   = __builtin_amdgcn_perm(a0[e], a1[e], 0x01000504u);
          t0[2*e+1] = __builtin_amdgcn_perm(a0[e], a1[e], 0x03020706u);
          t1[2*e]   = __builtin_amdgcn_perm(a2[e], a3[e], 0x01000504u);
          t1[2*e+1] = __builtin_amdgcn_perm(a2[e], a3[e], 0x03020706u);
        }
        if (py < px0 + 7) {          // diagonal-straddling chunk: mask tail
#pragma unroll
          for (int k = 0; k < 8; ++k)
            if (px0 + k > py) { t0[k] = 0; t1[k] = 0; }
        }
      }
      unsigned* d0 = &tile[0][row * PITCHW + 8 * c];
      unsigned* d1 = &tile[1][row * PITCHW + 8 * c];
      *reinterpret_cast<uint4*>(d0)     = *reinterpret_cast<uint4*>(&t0[0]);
      *reinterpret_cast<uint4*>(d0 + 4) = *reinterpret_cast<uint4*>(&t0[4]);
      *reinterpret_cast<uint4*>(d1)     = *reinterpret_cast<uint4*>(&t1[0]);
      *reinterpret_cast<uint4*>(d1 + 4) = *reinterpret_cast<uint4*>(&t1[4]);
    }
  }
  __syncthreads();

  float acc[4][8];
#pragma unroll
  for (int co = 0; co < 4; ++co)
#pragma unroll
    for (int j = 0; j < 8; ++j) acc[co][j] = 0.f;

#pragma unroll
  for (int cp = 0; cp < 2; ++cp) {
    // packed weights: block-uniform address -> s_load into SGPRs
    const unsigned* pw = reinterpret_cast<const unsigned*>(
        probs + (size_t)(g * 2 + cp) * L_DIM + 32);
    const unsigned* tb = tile[cp];

    for (int ky = 0; ky < K_SZ; ++ky) {
      const unsigned* rp = tb + (tyg + ky) * PITCHW + 8 * txg;
      unsigned q[24];
#pragma unroll
      for (int t4 = 0; t4 < 6; ++t4)
        *reinterpret_cast<uint4*>(&q[4 * t4]) =
            *reinterpret_cast<const uint4*>(rp + 4 * t4);
#pragma unroll
      for (int co = 0; co < 4; ++co) {
        const uint4* wq = reinterpret_cast<const uint4*>(pw + (co * K_SZ + ky) * 12);
        const uint4 w0 = wq[0], w1 = wq[1], w2 = wq[2];
        const unsigned wv[12] = {w0.x, w0.y, w0.z, w0.w,
                                 w1.x, w1.y, w1.z, w1.w,
                                 w2.x, w2.y, w2.z, w2.w};
#pragma unroll
        for (int kx = 0; kx < K_SZ; ++kx) {
#pragma unroll
          for (int j = 0; j < 8; ++j)
            acc[co][j] = dot2a(wv[kx], q[3 + kx + j], acc[co][j]);
        }
      }
    }
  }

  // epilogue: bias + causal re-mask
#pragma unroll
  for (int co = 0; co < 4; ++co) {
    const float bv = bias[g * 4 + co];
    float4 o0, o1;
    o0.x = (xb + 0 <= gy) ? acc[co][0] + bv : 0.f;
    o0.y = (xb + 1 <= gy) ? acc[co][1] + bv : 0.f;
    o0.z = (xb + 2 <= gy) ? acc[co][2] + bv : 0.f;
    o0.w = (xb + 3 <= gy) ? acc[co][3] + bv : 0.f;
    o1.x = (xb + 4 <= gy) ? acc[co][4] + bv : 0.f;
    o1.y = (xb + 5 <= gy) ? acc[co][5] + bv : 0.f;
    o1.z = (xb + 6 <= gy) ? acc[co][6] + bv : 0.f;
    o1.w = (xb + 7 <= gy) ? acc[co][7] + bv : 0.f;
    float* op = out + ((size_t)(b * C_CH + g * 4 + co) * L_DIM + gy) * L_DIM + xb;
    *reinterpret_cast<float4*>(op) = o0;
    *reinterpret_cast<float4*>(op + 4) = o1;
  }
}

extern "C" void kernel_launch(void* const* d_in, const int* in_sizes, int n_in,
                              void* d_out, int out_size, void* d_ws, size_t ws_size,
                              hipStream_t stream) {
  const float* scores = (const float*)d_in[0];
  const float* weight = (const float*)d_in[1];
  const float* bias   = (const float*)d_in[2];
  float* out = (float*)d_out;
  f16* probs = (f16*)d_ws;   // B*C*L*L fp16 = 256 MB (+ packed weights in plane-0 hole)

  pack_w_k<<<1, 256, 0, stream>>>(weight, probs);

  const int rows = B_SZ * C_CH * L_DIM;
  softmax_rows_k<<<rows / 4, 256, 0, stream>>>(scores, probs);

  dim3 grid(L_DIM / TX, L_DIM / TY, B_SZ * N_G);
  conv_k<<<grid, 256, 0, stream>>>(probs, bias, out);
}

// Round 6
// 605.609 us; speedup vs baseline: 1.5411x; 1.5411x over previous
//
#include <hip/hip_runtime.h>
#include <cmath>

#define L_DIM 2048
#define C_CH  16
#define B_SZ  2
#define N_G   4
#define C_PG  4
#define K_SZ  11

#define BX 64              /* out x per block */
#define BY 128             /* out y per block */
#define CHY 32             /* y chunk per staging pass */
#define QROWS 47           /* staged rows = CHY + 15 */
#define QPITCH 84          /* staged quads (u64) per row */
#define QROWB (QPITCH*8)   /* 672 bytes per staged row */
#define CXC 80             /* C xc columns per wave */
#define MP 52              /* C m-pitch in f16 (48 pad to 52, 8B-aligned rows) */
#define CLWB (CXC*MP*2)    /* 8320 bytes of C buffer per wave */

typedef _Float16 f16;
typedef __attribute__((ext_vector_type(2))) __fp16 fp16x2;
typedef __attribute__((ext_vector_type(8))) _Float16 f16x8;
typedef __attribute__((ext_vector_type(4))) float f32x4;

struct alignas(8) H4 { f16 x, y, z, w; };

// ---- pack weights into per-lane MFMA A-fragments in the probs plane-0 hole ----
// A[m=4kx+co][k]: lane l holds row m=16t+(l&15), k-slots (q=l>>4, j): ci=j&3,
// ky=8s+2q+(j>>2). Stored at plane0 row (g*2+s), f16 col 256 + (t*64+l)*8.
// Hole safety: softmax writes rows y<8 only at cols<=10; conv staging reads of
// rows<8 at cols>=32 are causally masked to zero.
__global__ void pack_w_k(const float* __restrict__ weight, f16* __restrict__ probs) {
  for (int e = threadIdx.x; e < 1536; e += 256) {
    const int l  = e & 63;
    const int r1 = e >> 6;        // 0..23
    const int t  = r1 % 3;
    const int r2 = r1 / 3;        // 0..7
    const int s  = r2 & 1;
    const int g  = r2 >> 1;
    const int m  = 16 * t + (l & 15);
    const int q  = l >> 4;
    const int kx = m >> 2, co = m & 3;
    f16 vals[8];
#pragma unroll
    for (int j = 0; j < 8; ++j) {
      const int ci = j & 3;
      const int ky = 8 * s + 2 * q + (j >> 2);
      float wv = 0.f;
      if (kx < K_SZ && ky < K_SZ)
        wv = weight[(((size_t)(g * 4 + co) * C_PG + ci) * K_SZ + ky) * K_SZ + kx];
      vals[j] = (f16)wv;
    }
    f16* dst = probs + (size_t)(g * 2 + s) * L_DIM + 256 + (size_t)(t * 64 + l) * 8;
#pragma unroll
    for (int j = 0; j < 8; ++j) dst[j] = vals[j];
  }
}

// ---------------- causal softmax: one wave per row ----------------
__global__ __launch_bounds__(256) void softmax_rows_k(
    const float* __restrict__ scores, f16* __restrict__ probs) {
  const int wid  = (blockIdx.x << 2) + (threadIdx.x >> 6);
  const int lane = threadIdx.x & 63;
  const int y    = wid & (L_DIM - 1);
  const float* srow = scores + (size_t)wid * L_DIM;

  float v[32];
#pragma unroll
  for (int j = 0; j < 8; ++j) {
    const int x = j * 256 + lane * 4;
    float4 f = make_float4(-INFINITY, -INFINITY, -INFINITY, -INFINITY);
    if (x <= y)
      f = *reinterpret_cast<const float4*>(srow + x);
    v[4*j+0] = (x + 0 <= y) ? f.x : -INFINITY;
    v[4*j+1] = (x + 1 <= y) ? f.y : -INFINITY;
    v[4*j+2] = (x + 2 <= y) ? f.z : -INFINITY;
    v[4*j+3] = (x + 3 <= y) ? f.w : -INFINITY;
  }
  float m = v[0];
#pragma unroll
  for (int i = 1; i < 32; ++i) m = fmaxf(m, v[i]);
#pragma unroll
  for (int off = 32; off >= 1; off >>= 1) m = fmaxf(m, __shfl_xor(m, off, 64));

  float s = 0.f;
#pragma unroll
  for (int i = 0; i < 32; ++i) { v[i] = __expf(v[i] - m); s += v[i]; }
#pragma unroll
  for (int off = 32; off >= 1; off >>= 1) s += __shfl_xor(s, off, 64);
  const float inv = 1.0f / s;

  f16* prow = probs + (size_t)wid * L_DIM;
#pragma unroll
  for (int j = 0; j < 8; ++j) {
    const int x = j * 256 + lane * 4;
    if (x > y) continue;
    H4 h;
    h.x = (f16)(v[4*j+0] * inv);
    h.y = (f16)(v[4*j+1] * inv);
    h.z = (f16)(v[4*j+2] * inv);
    h.w = (f16)(v[4*j+3] * inv);
    *reinterpret_cast<H4*>(prow + x) = h;
  }
}

// ---------------- shift-GEMM grouped conv via f16 MFMA ----------------
// per (b,g): C[m=4kx+co][xc] = sum_{ci,ky} W * P[ci][y+ky-5][xc]  (MFMA)
// out[co][y][x] = bias + sum_kx C[4kx+co][x+kx-5]                 (LDS epilogue)
__global__ __launch_bounds__(256) void conv_k(
    const f16* __restrict__ probs, const float* __restrict__ bias,
    float* __restrict__ out) {
  const int x0 = blockIdx.x * BX;
  const int Y0 = blockIdx.y * BY;
  const int bb = blockIdx.z >> 2;
  const int g  = blockIdx.z & 3;
  const int tid = threadIdx.x;
  const size_t plane = (size_t)L_DIM * L_DIM;

  float* outg = out + (size_t)(bb * C_CH + g * 4) * plane;

  // block entirely above the diagonal: zero stores only
  if (x0 >= Y0 + BY) {
    const int co = (tid >> 4) & 3;
    const int xq = tid & 15;
    const float4 z4 = make_float4(0.f, 0.f, 0.f, 0.f);
    for (int r = (tid >> 6); r < BY; r += 4) {
      float* op = outg + (size_t)co * plane + (size_t)(Y0 + r) * L_DIM + x0 + 4 * xq;
      *reinterpret_cast<float4*>(op) = z4;
    }
    return;
  }

  __shared__ unsigned long long Qs[QROWS * QPITCH];  // [row][x] 4-ci quads
  __shared__ f16 CLs[4 * CXC * MP];                  // per-wave C buffer

  const int lane = tid & 63;
  const int w    = tid >> 6;
  const int q    = lane >> 4;
  const int c    = lane & 15;

  // A fragments (held in registers for the whole kernel)
  f16x8 A00, A01, A10, A11, A20, A21;
  {
    const f16x8* at0 = reinterpret_cast<const f16x8*>(probs + (size_t)(g * 2 + 0) * L_DIM + 256);
    const f16x8* at1 = reinterpret_cast<const f16x8*>(probs + (size_t)(g * 2 + 1) * L_DIM + 256);
    A00 = at0[0 * 64 + lane]; A10 = at0[1 * 64 + lane]; A20 = at0[2 * 64 + lane];
    A01 = at1[0 * 64 + lane]; A11 = at1[1 * 64 + lane]; A21 = at1[2 * 64 + lane];
  }

  const float bs0 = bias[g * 4 + 0], bs1 = bias[g * 4 + 1];
  const float bs2 = bias[g * 4 + 2], bs3 = bias[g * 4 + 3];

  const f16* pstage = probs + (size_t)(bb * C_CH + g * C_PG) * plane;

  char* const qbase = reinterpret_cast<char*>(Qs);
  char* const clw   = reinterpret_cast<char*>(CLs) + w * CLWB;
  const char* const qlane = qbase + q * 1344 + c * 8;
  char* const clwr  = clw + c * 104 + q * 8;
  const char* const cle = clw + (lane + 3) * 104;

  for (int cb = Y0; cb < Y0 + BY; cb += CHY) {
    if (x0 > cb + CHY - 1) {
      // whole chunk above diagonal
      const int co = (tid >> 4) & 3;
      const int xq = tid & 15;
      const float4 z4 = make_float4(0.f, 0.f, 0.f, 0.f);
      for (int r = (tid >> 6); r < CHY; r += 4) {
        float* op = outg + (size_t)co * plane + (size_t)(cb + r) * L_DIM + x0 + 4 * xq;
        *reinterpret_cast<float4*>(op) = z4;
      }
      continue;
    }

    __syncthreads();   // protect previous chunk's readers
    // stage rows cb-5 .. cb+41 (47 rows) x 84 quads; 2 quads per unit
    for (int u = tid; u < QROWS * 42; u += 256) {
      const int r  = u / 42;
      const int xp = u - 42 * r;
      const int py = cb - 5 + r;
      const int px = x0 - 8 + 2 * xp;
      unsigned q0lo = 0, q0hi = 0, q1lo = 0, q1hi = 0;
      if (py >= 0 && py < L_DIM && px >= 0 && px <= py) {
        const size_t o = (size_t)py * L_DIM + px;
        const unsigned P0 = *reinterpret_cast<const unsigned*>(pstage + o);
        const unsigned P1 = *reinterpret_cast<const unsigned*>(pstage + plane + o);
        const unsigned P2 = *reinterpret_cast<const unsigned*>(pstage + 2 * plane + o);
        const unsigned P3 = *reinterpret_cast<const unsigned*>(pstage + 3 * plane + o);
        q0lo = __builtin_amdgcn_perm(P0, P1, 0x01000504u);
        q0hi = __builtin_amdgcn_perm(P2, P3, 0x01000504u);
        if (px + 1 <= py) {
          q1lo = __builtin_amdgcn_perm(P0, P1, 0x03020706u);
          q1hi = __builtin_amdgcn_perm(P2, P3, 0x03020706u);
        }
      }
      *reinterpret_cast<uint4*>(qbase + r * QROWB + xp * 16) =
          make_uint4(q0lo, q0hi, q1lo, q1hi);
    }
    __syncthreads();

    for (int i = 0; i < 8; ++i) {
      const int y = cb + w * 8 + i;          // wave-uniform
      float* orow = outg + (size_t)y * L_DIM + x0 + lane;
      if (y < x0) {                           // row fully above diagonal
        orow[0] = 0.f; orow[plane] = 0.f;
        orow[2 * plane] = 0.f; orow[3 * plane] = 0.f;
        continue;
      }
      const char* qy = qlane + (y - cb) * QROWB;

#pragma unroll
      for (int xs = 0; xs < 5; ++xs) {
        union { unsigned long long u[2]; f16x8 v; } b0, b1;
        b0.u[0] = *reinterpret_cast<const unsigned long long*>(qy + xs * 128 + 0);
        b0.u[1] = *reinterpret_cast<const unsigned long long*>(qy + xs * 128 + 672);
        b1.u[0] = *reinterpret_cast<const unsigned long long*>(qy + xs * 128 + 5376);
        b1.u[1] = *reinterpret_cast<const unsigned long long*>(qy + xs * 128 + 6048);
        f32x4 z = {0.f, 0.f, 0.f, 0.f};
        f32x4 c0 = __builtin_amdgcn_mfma_f32_16x16x32_f16(A00, b0.v, z, 0, 0, 0);
        c0 = __builtin_amdgcn_mfma_f32_16x16x32_f16(A01, b1.v, c0, 0, 0, 0);
        f32x4 c1 = __builtin_amdgcn_mfma_f32_16x16x32_f16(A10, b0.v, z, 0, 0, 0);
        c1 = __builtin_amdgcn_mfma_f32_16x16x32_f16(A11, b1.v, c1, 0, 0, 0);
        f32x4 c2 = __builtin_amdgcn_mfma_f32_16x16x32_f16(A20, b0.v, z, 0, 0, 0);
        c2 = __builtin_amdgcn_mfma_f32_16x16x32_f16(A21, b1.v, c2, 0, 0, 0);

        union { fp16x2 h[2]; unsigned long long u; } pk;
        pk.h[0] = __builtin_amdgcn_cvt_pkrtz(c0[0], c0[1]);
        pk.h[1] = __builtin_amdgcn_cvt_pkrtz(c0[2], c0[3]);
        *reinterpret_cast<unsigned long long*>(clwr + xs * 1664 + 0) = pk.u;
        pk.h[0] = __builtin_amdgcn_cvt_pkrtz(c1[0], c1[1]);
        pk.h[1] = __builtin_amdgcn_cvt_pkrtz(c1[2], c1[3]);
        *reinterpret_cast<unsigned long long*>(clwr + xs * 1664 + 32) = pk.u;
        pk.h[0] = __builtin_amdgcn_cvt_pkrtz(c2[0], c2[1]);
        pk.h[1] = __builtin_amdgcn_cvt_pkrtz(c2[2], c2[3]);
        *reinterpret_cast<unsigned long long*>(clwr + xs * 1664 + 64) = pk.u;
      }

      // epilogue: out[co][x] = bias + sum_kx C[4kx+co][x+kx-5], f32 accumulate
      float s0 = 0.f, s1 = 0.f, s2 = 0.f, s3 = 0.f;
#pragma unroll
      for (int kx = 0; kx < K_SZ; ++kx) {
        union { unsigned long long u; f16 h[4]; } cv;
        cv.u = *reinterpret_cast<const unsigned long long*>(cle + kx * 112);
        s0 += (float)cv.h[0]; s1 += (float)cv.h[1];
        s2 += (float)cv.h[2]; s3 += (float)cv.h[3];
      }
      const bool act = (x0 + lane) <= y;
      orow[0]         = act ? s0 + bs0 : 0.f;
      orow[plane]     = act ? s1 + bs1 : 0.f;
      orow[2 * plane] = act ? s2 + bs2 : 0.f;
      orow[3 * plane] = act ? s3 + bs3 : 0.f;
    }
  }
}

extern "C" void kernel_launch(void* const* d_in, const int* in_sizes, int n_in,
                              void* d_out, int out_size, void* d_ws, size_t ws_size,
                              hipStream_t stream) {
  const float* scores = (const float*)d_in[0];
  const float* weight = (const float*)d_in[1];
  const float* bias   = (const float*)d_in[2];
  float* outp = (float*)d_out;
  f16* probs = (f16*)d_ws;   // B*C*L*L fp16 = 256 MB (+ A-frag table in plane-0 hole)

  pack_w_k<<<1, 256, 0, stream>>>(weight, probs);

  const int rows = B_SZ * C_CH * L_DIM;
  softmax_rows_k<<<rows / 4, 256, 0, stream>>>(scores, probs);

  dim3 grid(L_DIM / BX, L_DIM / BY, B_SZ * N_G);
  conv_k<<<grid, 256, 0, stream>>>(probs, bias, outp);
}

// Round 7
// 513.421 us; speedup vs baseline: 1.8178x; 1.1796x over previous
//
#include <hip/hip_runtime.h>
#include <cmath>

#define L_DIM 2048
#define C_CH  16
#define B_SZ  2
#define N_G   4
#define C_PG  4
#define K_SZ  11

#define BX 64              /* out x per block */
#define BY 128             /* out y per block */
#define CHY 16             /* y chunk per staging pass */
#define QROWS 31           /* staged rows = CHY + 15 (k pads ky to 16) */
#define QPITCH 84          /* staged quads (u64) per row */
#define QROWB (QPITCH*8)   /* 672 bytes per staged row */
#define NUNIT (QROWS*42)   /* 1302 staging units (2 quads each) */
#define NU 6               /* ceil(NUNIT/256) */
#define CXC 80             /* C xc columns per wave */
#define MP 52              /* C m-pitch in f16 (48 pad to 52, 8B-aligned, 2-way) */
#define CLWB (CXC*MP*2)    /* 8320 bytes of C buffer per wave */

typedef _Float16 f16;
typedef __attribute__((ext_vector_type(2))) __fp16 fp16x2;
typedef __attribute__((ext_vector_type(8))) _Float16 f16x8;
typedef __attribute__((ext_vector_type(4))) float f32x4;
typedef unsigned long long u64;

struct alignas(8) H4 { f16 x, y, z, w; };

// ---- pack weights into per-lane MFMA A-fragments in the probs plane-0 hole ----
// A[m=4kx+co][k]: lane l holds row m=16t+(l&15), k-slots (q=l>>4, j): ci=j&3,
// ky=8s+2q+(j>>2). Stored at plane0 row (g*2+s), f16 col 256 + (t*64+l)*8.
// Hole safety: softmax writes rows y<8 only at cols<=10; conv staging reads of
// rows<8 at cols>7 are causally masked to zero.
__global__ void pack_w_k(const float* __restrict__ weight, f16* __restrict__ probs) {
  for (int e = threadIdx.x; e < 1536; e += 256) {
    const int l  = e & 63;
    const int r1 = e >> 6;        // 0..23
    const int t  = r1 % 3;
    const int r2 = r1 / 3;        // 0..7
    const int s  = r2 & 1;
    const int g  = r2 >> 1;
    const int m  = 16 * t + (l & 15);
    const int q  = l >> 4;
    const int kx = m >> 2, co = m & 3;
    f16 vals[8];
#pragma unroll
    for (int j = 0; j < 8; ++j) {
      const int ci = j & 3;
      const int ky = 8 * s + 2 * q + (j >> 2);
      float wv = 0.f;
      if (kx < K_SZ && ky < K_SZ)
        wv = weight[(((size_t)(g * 4 + co) * C_PG + ci) * K_SZ + ky) * K_SZ + kx];
      vals[j] = (f16)wv;
    }
    f16* dst = probs + (size_t)(g * 2 + s) * L_DIM + 256 + (size_t)(t * 64 + l) * 8;
#pragma unroll
    for (int j = 0; j < 8; ++j) dst[j] = vals[j];
  }
}

// ---------------- causal softmax: one wave per row ----------------
__global__ __launch_bounds__(256) void softmax_rows_k(
    const float* __restrict__ scores, f16* __restrict__ probs) {
  const int wid  = (blockIdx.x << 2) + (threadIdx.x >> 6);
  const int lane = threadIdx.x & 63;
  const int y    = wid & (L_DIM - 1);
  const float* srow = scores + (size_t)wid * L_DIM;

  float v[32];
#pragma unroll
  for (int j = 0; j < 8; ++j) {
    const int x = j * 256 + lane * 4;
    float4 f = make_float4(-INFINITY, -INFINITY, -INFINITY, -INFINITY);
    if (x <= y)
      f = *reinterpret_cast<const float4*>(srow + x);
    v[4*j+0] = (x + 0 <= y) ? f.x : -INFINITY;
    v[4*j+1] = (x + 1 <= y) ? f.y : -INFINITY;
    v[4*j+2] = (x + 2 <= y) ? f.z : -INFINITY;
    v[4*j+3] = (x + 3 <= y) ? f.w : -INFINITY;
  }
  float m = v[0];
#pragma unroll
  for (int i = 1; i < 32; ++i) m = fmaxf(m, v[i]);
#pragma unroll
  for (int off = 32; off >= 1; off >>= 1) m = fmaxf(m, __shfl_xor(m, off, 64));

  float s = 0.f;
#pragma unroll
  for (int i = 0; i < 32; ++i) { v[i] = __expf(v[i] - m); s += v[i]; }
#pragma unroll
  for (int off = 32; off >= 1; off >>= 1) s += __shfl_xor(s, off, 64);
  const float inv = 1.0f / s;

  f16* prow = probs + (size_t)wid * L_DIM;
#pragma unroll
  for (int j = 0; j < 8; ++j) {
    const int x = j * 256 + lane * 4;
    if (x > y) continue;
    H4 h;
    h.x = (f16)(v[4*j+0] * inv);
    h.y = (f16)(v[4*j+1] * inv);
    h.z = (f16)(v[4*j+2] * inv);
    h.w = (f16)(v[4*j+3] * inv);
    *reinterpret_cast<H4*>(prow + x) = h;
  }
}

// ---------------- shift-GEMM grouped conv via f16 MFMA ----------------
// per (b,g): C[m=4kx+co][xc] = sum_{ci,ky} W * P[ci][y+ky-5][xc]  (MFMA)
// out[co][y][x] = bias + sum_kx C[4kx+co][x+kx-5]                 (LDS epilogue)
__global__ __launch_bounds__(256, 3) void conv_k(
    const f16* __restrict__ probs, const float* __restrict__ bias,
    float* __restrict__ out) {
  const int x0 = blockIdx.x * BX;
  const int Y0 = blockIdx.y * BY;
  const int bb = blockIdx.z >> 2;
  const int g  = blockIdx.z & 3;
  const int tid = threadIdx.x;
  const size_t plane = (size_t)L_DIM * L_DIM;

  float* outg = out + (size_t)(bb * C_CH + g * 4) * plane;

  // block entirely above the diagonal: zero stores only
  if (x0 >= Y0 + BY) {
    const int co = (tid >> 4) & 3;
    const int xq = tid & 15;
    const float4 z4 = make_float4(0.f, 0.f, 0.f, 0.f);
    for (int r = (tid >> 6); r < BY; r += 4) {
      float* op = outg + (size_t)co * plane + (size_t)(Y0 + r) * L_DIM + x0 + 4 * xq;
      *reinterpret_cast<float4*>(op) = z4;
    }
    return;
  }

  __shared__ u64 Qs[QROWS * QPITCH];   // [row][x] 4-ci quads (20832 B)
  __shared__ f16 CLs[4 * CXC * MP];    // per-wave C buffer (33280 B)

  const int lane = tid & 63;
  const int w    = tid >> 6;
  const int q    = lane >> 4;
  const int c    = lane & 15;

  // A fragments (held in registers for the whole kernel)
  f16x8 A00, A01, A10, A11, A20, A21;
  {
    const f16x8* at0 = reinterpret_cast<const f16x8*>(probs + (size_t)(g * 2 + 0) * L_DIM + 256);
    const f16x8* at1 = reinterpret_cast<const f16x8*>(probs + (size_t)(g * 2 + 1) * L_DIM + 256);
    A00 = at0[0 * 64 + lane]; A10 = at0[1 * 64 + lane]; A20 = at0[2 * 64 + lane];
    A01 = at1[0 * 64 + lane]; A11 = at1[1 * 64 + lane]; A21 = at1[2 * 64 + lane];
  }

  const float bs0 = bias[g * 4 + 0], bs1 = bias[g * 4 + 1];
  const float bs2 = bias[g * 4 + 2], bs3 = bias[g * 4 + 3];

  const f16* pstage = probs + (size_t)(bb * C_CH + g * C_PG) * plane;

  char* const qbase = reinterpret_cast<char*>(Qs);
  char* const clw   = reinterpret_cast<char*>(CLs) + w * CLWB;
  const char* const qlane = qbase + q * 1344 + c * 8;
  char* const clwr  = clw + c * 104 + q * 8;
  const char* const cle = clw + (lane + 3) * 104;

  for (int cb = Y0; cb < Y0 + BY; cb += CHY) {
    if (x0 > cb + CHY - 1) {
      // whole chunk above diagonal
      const int co = (tid >> 4) & 3;
      const int xq = tid & 15;
      const float4 z4 = make_float4(0.f, 0.f, 0.f, 0.f);
      for (int r = (tid >> 6); r < CHY; r += 4) {
        float* op = outg + (size_t)co * plane + (size_t)(cb + r) * L_DIM + x0 + 4 * xq;
        *reinterpret_cast<float4*>(op) = z4;
      }
      continue;
    }

    // ---- phase 1: issue ALL staging loads (independent, latency overlapped)
    unsigned lv[NU][4];
#pragma unroll
    for (int k = 0; k < NU; ++k) {
      const int u  = tid + 256 * k;
      const int r  = u / 42;
      const int xp = u - 42 * r;
      const int py = cb - 5 + r;
      const int px = x0 - 8 + 2 * xp;
      lv[k][0] = 0; lv[k][1] = 0; lv[k][2] = 0; lv[k][3] = 0;
      if (u < NUNIT && py >= 0 && py < L_DIM && px >= 0 && px <= py) {
        const size_t o = (size_t)py * L_DIM + px;
        lv[k][0] = *reinterpret_cast<const unsigned*>(pstage + o);
        lv[k][1] = *reinterpret_cast<const unsigned*>(pstage + plane + o);
        lv[k][2] = *reinterpret_cast<const unsigned*>(pstage + 2 * plane + o);
        lv[k][3] = *reinterpret_cast<const unsigned*>(pstage + 3 * plane + o);
      }
    }
    __syncthreads();   // previous chunk's LDS readers done before overwrite
    // ---- phase 2: interleave channels + LDS write
#pragma unroll
    for (int k = 0; k < NU; ++k) {
      const int u  = tid + 256 * k;
      if (u < NUNIT) {
        const int r  = u / 42;
        const int xp = u - 42 * r;
        const int py = cb - 5 + r;
        const int px = x0 - 8 + 2 * xp;
        const unsigned q0lo = __builtin_amdgcn_perm(lv[k][0], lv[k][1], 0x01000504u);
        const unsigned q0hi = __builtin_amdgcn_perm(lv[k][2], lv[k][3], 0x01000504u);
        unsigned q1lo = 0, q1hi = 0;
        if (px >= 0 && px + 1 <= py) {
          q1lo = __builtin_amdgcn_perm(lv[k][0], lv[k][1], 0x03020706u);
          q1hi = __builtin_amdgcn_perm(lv[k][2], lv[k][3], 0x03020706u);
        }
        *reinterpret_cast<uint4*>(qbase + r * QROWB + xp * 16) =
            make_uint4(q0lo, q0hi, q1lo, q1hi);
      }
    }
    __syncthreads();

    for (int i = 0; i < CHY / 4; ++i) {
      const int y = cb + w * (CHY / 4) + i;   // wave-uniform
      float* orow = outg + (size_t)y * L_DIM + x0 + lane;
      if (y < x0) {                            // row fully above diagonal
        orow[0] = 0.f; orow[plane] = 0.f;
        orow[2 * plane] = 0.f; orow[3 * plane] = 0.f;
        continue;
      }
      const char* qy = qlane + (y - cb) * QROWB;

      // hoist all 20 B-fragment reads (one lgkm wait, independent MFMAs)
      u64 b00[5], b01[5], b10[5], b11[5];
#pragma unroll
      for (int xs = 0; xs < 5; ++xs) {
        b00[xs] = *reinterpret_cast<const u64*>(qy + xs * 128 + 0);
        b01[xs] = *reinterpret_cast<const u64*>(qy + xs * 128 + 672);
        b10[xs] = *reinterpret_cast<const u64*>(qy + xs * 128 + 5376);
        b11[xs] = *reinterpret_cast<const u64*>(qy + xs * 128 + 6048);
      }

#pragma unroll
      for (int xs = 0; xs < 5; ++xs) {
        union { u64 u[2]; f16x8 v; } B0, B1;
        B0.u[0] = b00[xs]; B0.u[1] = b01[xs];
        B1.u[0] = b10[xs]; B1.u[1] = b11[xs];
        f32x4 z = {0.f, 0.f, 0.f, 0.f};
        f32x4 c0 = __builtin_amdgcn_mfma_f32_16x16x32_f16(A00, B0.v, z, 0, 0, 0);
        c0 = __builtin_amdgcn_mfma_f32_16x16x32_f16(A01, B1.v, c0, 0, 0, 0);
        f32x4 c1 = __builtin_amdgcn_mfma_f32_16x16x32_f16(A10, B0.v, z, 0, 0, 0);
        c1 = __builtin_amdgcn_mfma_f32_16x16x32_f16(A11, B1.v, c1, 0, 0, 0);
        f32x4 c2 = __builtin_amdgcn_mfma_f32_16x16x32_f16(A20, B0.v, z, 0, 0, 0);
        c2 = __builtin_amdgcn_mfma_f32_16x16x32_f16(A21, B1.v, c2, 0, 0, 0);

        union { fp16x2 h[2]; u64 u; } pk;
        pk.h[0] = __builtin_amdgcn_cvt_pkrtz(c0[0], c0[1]);
        pk.h[1] = __builtin_amdgcn_cvt_pkrtz(c0[2], c0[3]);
        *reinterpret_cast<u64*>(clwr + xs * 1664 + 0) = pk.u;
        pk.h[0] = __builtin_amdgcn_cvt_pkrtz(c1[0], c1[1]);
        pk.h[1] = __builtin_amdgcn_cvt_pkrtz(c1[2], c1[3]);
        *reinterpret_cast<u64*>(clwr + xs * 1664 + 32) = pk.u;
        pk.h[0] = __builtin_amdgcn_cvt_pkrtz(c2[0], c2[1]);
        pk.h[1] = __builtin_amdgcn_cvt_pkrtz(c2[2], c2[3]);
        *reinterpret_cast<u64*>(clwr + xs * 1664 + 64) = pk.u;
      }

      // epilogue: out[co][x] = bias + sum_kx C[4kx+co][x+kx-5], f32 accumulate
      float s0 = 0.f, s1 = 0.f, s2 = 0.f, s3 = 0.f;
#pragma unroll
      for (int kx = 0; kx < K_SZ; ++kx) {
        union { u64 u; f16 h[4]; } cv;
        cv.u = *reinterpret_cast<const u64*>(cle + kx * 112);
        s0 += (float)cv.h[0]; s1 += (float)cv.h[1];
        s2 += (float)cv.h[2]; s3 += (float)cv.h[3];
      }
      const bool act = (x0 + lane) <= y;
      orow[0]         = act ? s0 + bs0 : 0.f;
      orow[plane]     = act ? s1 + bs1 : 0.f;
      orow[2 * plane] = act ? s2 + bs2 : 0.f;
      orow[3 * plane] = act ? s3 + bs3 : 0.f;
    }
  }
}

extern "C" void kernel_launch(void* const* d_in, const int* in_sizes, int n_in,
                              void* d_out, int out_size, void* d_ws, size_t ws_size,
                              hipStream_t stream) {
  const float* scores = (const float*)d_in[0];
  const float* weight = (const float*)d_in[1];
  const float* bias   = (const float*)d_in[2];
  float* outp = (float*)d_out;
  f16* probs = (f16*)d_ws;   // B*C*L*L fp16 = 256 MB (+ A-frag table in plane-0 hole)

  pack_w_k<<<1, 256, 0, stream>>>(weight, probs);

  const int rows = B_SZ * C_CH * L_DIM;
  softmax_rows_k<<<rows / 4, 256, 0, stream>>>(scores, probs);

  dim3 grid(L_DIM / BX, L_DIM / BY, B_SZ * N_G);
  conv_k<<<grid, 256, 0, stream>>>(probs, bias, outp);
}

// Round 8
// 396.579 us; speedup vs baseline: 2.3534x; 1.2946x over previous
//
#include <hip/hip_runtime.h>
#include <cmath>

#define L_DIM 2048
#define C_CH  16
#define B_SZ  2
#define N_G   4
#define C_PG  4
#define K_SZ  11

#define BX 64              /* out x per block */
#define BY 128             /* out y per block */
#define CHY 16             /* y chunk per staging pass */
#define QROWS 31           /* staged rows = CHY + 15 */
#define QPITCH 84          /* staged quads (u64 per x) per row */
#define QROWB (QPITCH*8)   /* 672 bytes per staged row */
#define NUNIT (QROWS*42)   /* 1302 16B staging units */
#define NU 6               /* ceil(NUNIT/256) */
#define CXC 80             /* C xc columns per wave */
#define MP 52              /* C m-pitch in f16 */
#define CLWB (CXC*MP*2)    /* 8320 bytes of C buffer per wave */

typedef _Float16 f16;
typedef __attribute__((ext_vector_type(2))) __fp16 fp16x2;
typedef __attribute__((ext_vector_type(8))) _Float16 f16x8;
typedef __attribute__((ext_vector_type(4))) float f32x4;
typedef unsigned long long u64;

struct alignas(8) H4 { f16 x, y, z, w; };
union H8U { H4 h[2]; uint4 u; };

// ---- pack weights into per-lane MFMA A-fragments, quad-plane-0 hole ----
// entry e=t*64+l for (g,s): 16B at byte ((g*2+s)*2048 + 512)*8 + e*16.
// Hole safety: softmax writes row y<8 only quads < 16; conv data-reads of
// rows 0..7 stay below quad ~110. A-table lives at quads 512..896.
__global__ void pack_w_k(const float* __restrict__ weight, u64* __restrict__ qprobs) {
  for (int e = threadIdx.x; e < 1536; e += 256) {
    const int l  = e & 63;
    const int r1 = e >> 6;        // 0..23
    const int t  = r1 % 3;
    const int r2 = r1 / 3;        // 0..7
    const int s  = r2 & 1;
    const int g  = r2 >> 1;
    const int m  = 16 * t + (l & 15);
    const int q  = l >> 4;
    const int kx = m >> 2, co = m & 3;
    f16 vals[8];
#pragma unroll
    for (int j = 0; j < 8; ++j) {
      const int ci = j & 3;
      const int ky = 8 * s + 2 * q + (j >> 2);
      float wv = 0.f;
      if (kx < K_SZ && ky < K_SZ)
        wv = weight[(((size_t)(g * 4 + co) * C_PG + ci) * K_SZ + ky) * K_SZ + kx];
      vals[j] = (f16)wv;
    }
    f16* dst = reinterpret_cast<f16*>(
        reinterpret_cast<char*>(qprobs) +
        ((size_t)(g * 2 + s) * L_DIM + 512) * 8 + (size_t)(t * 64 + l) * 16);
#pragma unroll
    for (int j = 0; j < 8; ++j) dst[j] = vals[j];
  }
}

// ---------------- causal softmax -> channel-quad probs ----------------
// block = (b,g,y): 4 waves, wave w covers x in [512w, 512w+512), all 4 channels.
// Writes u64 quads {c0,c1,c2,c3}(x); zero band through x = y+11.
__global__ __launch_bounds__(256) void softmax_q_k(
    const float* __restrict__ scores, u64* __restrict__ qprobs) {
  const int bid = blockIdx.x;
  const int zg  = bid & 7;            // (b,g) -> XCD-pinned
  const int y   = bid >> 3;
  const int b   = zg >> 2, g = zg & 3;
  const int tid = threadIdx.x;
  const int w    = tid >> 6;
  const int lane = tid & 63;

  __shared__ float mred[4][4];
  __shared__ float sred[4][4];

  const float* sbase = scores + ((size_t)(b * C_CH + g * 4) * L_DIM + y) * L_DIM;
  const size_t plane = (size_t)L_DIM * L_DIM;

  // load (masked) values: v[cc][j*2+e], x = 512w + 128j + 2lane + e
  float v[4][8];
#pragma unroll
  for (int cc = 0; cc < 4; ++cc)
#pragma unroll
    for (int j = 0; j < 4; ++j) {
      const int x = 512 * w + 128 * j + 2 * lane;
      float2 f = make_float2(-INFINITY, -INFINITY);
      if (512 * w + 128 * j <= y) {
        f = *reinterpret_cast<const float2*>(sbase + cc * plane + x);
        if (x > y)     f.x = -INFINITY;
        if (x + 1 > y) f.y = -INFINITY;
      }
      v[cc][2 * j]     = f.x;
      v[cc][2 * j + 1] = f.y;
    }

  // max reduce
  float ml[4];
#pragma unroll
  for (int cc = 0; cc < 4; ++cc) {
    float m = v[cc][0];
#pragma unroll
    for (int i = 1; i < 8; ++i) m = fmaxf(m, v[cc][i]);
#pragma unroll
    for (int off = 32; off >= 1; off >>= 1) m = fmaxf(m, __shfl_xor(m, off, 64));
    ml[cc] = m;
  }
  if (lane == 0) {
#pragma unroll
    for (int cc = 0; cc < 4; ++cc) mred[w][cc] = ml[cc];
  }
  __syncthreads();
  float mf[4];
#pragma unroll
  for (int cc = 0; cc < 4; ++cc)
    mf[cc] = fmaxf(fmaxf(mred[0][cc], mred[1][cc]),
                   fmaxf(mred[2][cc], mred[3][cc]));

  // exp + sum reduce
  float sl[4];
#pragma unroll
  for (int cc = 0; cc < 4; ++cc) {
    float s = 0.f;
#pragma unroll
    for (int i = 0; i < 8; ++i) { v[cc][i] = __expf(v[cc][i] - mf[cc]); s += v[cc][i]; }
#pragma unroll
    for (int off = 32; off >= 1; off >>= 1) s += __shfl_xor(s, off, 64);
    sl[cc] = s;
  }
  if (lane == 0) {
#pragma unroll
    for (int cc = 0; cc < 4; ++cc) sred[w][cc] = sl[cc];
  }
  __syncthreads();
  float inv[4];
#pragma unroll
  for (int cc = 0; cc < 4; ++cc)
    inv[cc] = 1.0f / (sred[0][cc] + sred[1][cc] + sred[2][cc] + sred[3][cc]);

  // store quads; write every chunk whose start <= y+11 (zero band)
  u64* qrow = qprobs + ((size_t)zg * L_DIM + y) * L_DIM;
#pragma unroll
  for (int j = 0; j < 4; ++j) {
    const int xbase = 512 * w + 128 * j;
    if (xbase > y + 11) continue;
    const int x = xbase + 2 * lane;
    H8U o;
    o.h[0].x = (f16)(v[0][2*j]   * inv[0]);
    o.h[0].y = (f16)(v[1][2*j]   * inv[1]);
    o.h[0].z = (f16)(v[2][2*j]   * inv[2]);
    o.h[0].w = (f16)(v[3][2*j]   * inv[3]);
    o.h[1].x = (f16)(v[0][2*j+1] * inv[0]);
    o.h[1].y = (f16)(v[1][2*j+1] * inv[1]);
    o.h[1].z = (f16)(v[2][2*j+1] * inv[2]);
    o.h[1].w = (f16)(v[3][2*j+1] * inv[3]);
    *reinterpret_cast<uint4*>(qrow + x) = o.u;
  }
}

// ---------------- shift-GEMM grouped conv via f16 MFMA ----------------
__global__ __launch_bounds__(256, 3) void conv_k(
    const u64* __restrict__ qprobs, const float* __restrict__ bias,
    float* __restrict__ out) {
  const int bid = blockIdx.x;
  const int zg  = bid & 7;            // (b,g) -> XCD-pinned
  const int lin = bid >> 3;           // 0..511
  const int xt  = lin & 31, yt = lin >> 5;
  const int x0 = xt * BX;
  const int Y0 = yt * BY;
  const int bb = zg >> 2, g = zg & 3;
  const int tid = threadIdx.x;
  const size_t plane = (size_t)L_DIM * L_DIM;

  float* outg = out + (size_t)(bb * C_CH + g * 4) * plane;

  // block entirely above the diagonal: zero stores only
  if (x0 >= Y0 + BY) {
    const int co = (tid >> 4) & 3;
    const int xq = tid & 15;
    const float4 z4 = make_float4(0.f, 0.f, 0.f, 0.f);
    for (int r = (tid >> 6); r < BY; r += 4) {
      float* op = outg + (size_t)co * plane + (size_t)(Y0 + r) * L_DIM + x0 + 4 * xq;
      *reinterpret_cast<float4*>(op) = z4;
    }
    return;
  }

  __shared__ u64 Qs[QROWS * QPITCH];   // [row][x] quads (20832 B)
  __shared__ f16 CLs[4 * CXC * MP];    // per-wave C buffer (33280 B)

  const int lane = tid & 63;
  const int w    = tid >> 6;
  const int q    = lane >> 4;
  const int c    = lane & 15;

  // A fragments from quad-plane-0 hole
  f16x8 A00, A01, A10, A11, A20, A21;
  {
    const char* qp0 = reinterpret_cast<const char*>(qprobs);
    const char* at0 = qp0 + ((size_t)(g * 2 + 0) * L_DIM + 512) * 8;
    const char* at1 = qp0 + ((size_t)(g * 2 + 1) * L_DIM + 512) * 8;
    A00 = *reinterpret_cast<const f16x8*>(at0 + (0 * 64 + lane) * 16);
    A10 = *reinterpret_cast<const f16x8*>(at0 + (1 * 64 + lane) * 16);
    A20 = *reinterpret_cast<const f16x8*>(at0 + (2 * 64 + lane) * 16);
    A01 = *reinterpret_cast<const f16x8*>(at1 + (0 * 64 + lane) * 16);
    A11 = *reinterpret_cast<const f16x8*>(at1 + (1 * 64 + lane) * 16);
    A21 = *reinterpret_cast<const f16x8*>(at1 + (2 * 64 + lane) * 16);
  }

  const float bs0 = bias[g * 4 + 0], bs1 = bias[g * 4 + 1];
  const float bs2 = bias[g * 4 + 2], bs3 = bias[g * 4 + 3];

  const u64* qplane = qprobs + (size_t)zg * plane;
  const int qx0 = x0 - 8;

  char* const qbase = reinterpret_cast<char*>(Qs);
  char* const clw   = reinterpret_cast<char*>(CLs) + w * CLWB;
  const char* const qlane = qbase + q * 1344 + c * 8;
  char* const clwr  = clw + c * 104 + q * 8;
  const char* const cle = clw + (lane + 3) * 104;

  for (int cb = Y0; cb < Y0 + BY; cb += CHY) {
    if (x0 > cb + CHY - 1) {
      const int co = (tid >> 4) & 3;
      const int xq = tid & 15;
      const float4 z4 = make_float4(0.f, 0.f, 0.f, 0.f);
      for (int r = (tid >> 6); r < CHY; r += 4) {
        float* op = outg + (size_t)co * plane + (size_t)(cb + r) * L_DIM + x0 + 4 * xq;
        *reinterpret_cast<float4*>(op) = z4;
      }
      continue;
    }

    // ---- phase 1: issue all staging loads (quad layout: direct 16B copies)
    uint4 sv[NU];
#pragma unroll
    for (int k = 0; k < NU; ++k) {
      const int u   = tid + 256 * k;    // 16B unit
      const int r   = u / 42;
      const int c16 = u - 42 * r;
      const int py  = cb - 5 + r;
      const int qc0 = qx0 + 2 * c16;
      sv[k] = make_uint4(0u, 0u, 0u, 0u);
      if (u < NUNIT && py >= 0 && py < L_DIM && qc0 >= 0 && qc0 <= L_DIM - 2)
        sv[k] = *reinterpret_cast<const uint4*>(qplane + (size_t)py * L_DIM + qc0);
    }
    __syncthreads();   // previous chunk's LDS readers done before overwrite
    // ---- phase 2: LDS write
#pragma unroll
    for (int k = 0; k < NU; ++k) {
      const int u   = tid + 256 * k;
      if (u < NUNIT) {
        const int r   = u / 42;
        const int c16 = u - 42 * r;
        *reinterpret_cast<uint4*>(qbase + r * QROWB + c16 * 16) = sv[k];
      }
    }
    __syncthreads();

    for (int i = 0; i < CHY / 4; ++i) {
      const int y = cb + w * (CHY / 4) + i;   // wave-uniform
      float* orow = outg + (size_t)y * L_DIM + x0 + lane;
      if (y < x0) {                            // row fully above diagonal
        orow[0] = 0.f; orow[plane] = 0.f;
        orow[2 * plane] = 0.f; orow[3 * plane] = 0.f;
        continue;
      }
      const char* qy = qlane + (y - cb) * QROWB;

      // hoist all 20 B-fragment reads
      u64 b00[5], b01[5], b10[5], b11[5];
#pragma unroll
      for (int xs = 0; xs < 5; ++xs) {
        b00[xs] = *reinterpret_cast<const u64*>(qy + xs * 128 + 0);
        b01[xs] = *reinterpret_cast<const u64*>(qy + xs * 128 + 672);
        b10[xs] = *reinterpret_cast<const u64*>(qy + xs * 128 + 5376);
        b11[xs] = *reinterpret_cast<const u64*>(qy + xs * 128 + 6048);
      }

#pragma unroll
      for (int xs = 0; xs < 5; ++xs) {
        union { u64 u[2]; f16x8 v; } B0, B1;
        B0.u[0] = b00[xs]; B0.u[1] = b01[xs];
        B1.u[0] = b10[xs]; B1.u[1] = b11[xs];
        f32x4 z = {0.f, 0.f, 0.f, 0.f};
        f32x4 c0 = __builtin_amdgcn_mfma_f32_16x16x32_f16(A00, B0.v, z, 0, 0, 0);
        c0 = __builtin_amdgcn_mfma_f32_16x16x32_f16(A01, B1.v, c0, 0, 0, 0);
        f32x4 c1 = __builtin_amdgcn_mfma_f32_16x16x32_f16(A10, B0.v, z, 0, 0, 0);
        c1 = __builtin_amdgcn_mfma_f32_16x16x32_f16(A11, B1.v, c1, 0, 0, 0);
        f32x4 c2 = __builtin_amdgcn_mfma_f32_16x16x32_f16(A20, B0.v, z, 0, 0, 0);
        c2 = __builtin_amdgcn_mfma_f32_16x16x32_f16(A21, B1.v, c2, 0, 0, 0);

        union { fp16x2 h[2]; u64 u; } pk;
        pk.h[0] = __builtin_amdgcn_cvt_pkrtz(c0[0], c0[1]);
        pk.h[1] = __builtin_amdgcn_cvt_pkrtz(c0[2], c0[3]);
        *reinterpret_cast<u64*>(clwr + xs * 1664 + 0) = pk.u;
        pk.h[0] = __builtin_amdgcn_cvt_pkrtz(c1[0], c1[1]);
        pk.h[1] = __builtin_amdgcn_cvt_pkrtz(c1[2], c1[3]);
        *reinterpret_cast<u64*>(clwr + xs * 1664 + 32) = pk.u;
        pk.h[0] = __builtin_amdgcn_cvt_pkrtz(c2[0], c2[1]);
        pk.h[1] = __builtin_amdgcn_cvt_pkrtz(c2[2], c2[3]);
        *reinterpret_cast<u64*>(clwr + xs * 1664 + 64) = pk.u;
      }

      // epilogue: out[co][x] = bias + sum_kx C[4kx+co][x+kx-5]
      float s0 = 0.f, s1 = 0.f, s2 = 0.f, s3 = 0.f;
#pragma unroll
      for (int kx = 0; kx < K_SZ; ++kx) {
        union { u64 u; f16 h[4]; } cv;
        cv.u = *reinterpret_cast<const u64*>(cle + kx * 112);
        s0 += (float)cv.h[0]; s1 += (float)cv.h[1];
        s2 += (float)cv.h[2]; s3 += (float)cv.h[3];
      }
      const bool act = (x0 + lane) <= y;
      orow[0]         = act ? s0 + bs0 : 0.f;
      orow[plane]     = act ? s1 + bs1 : 0.f;
      orow[2 * plane] = act ? s2 + bs2 : 0.f;
      orow[3 * plane] = act ? s3 + bs3 : 0.f;
    }
  }
}

extern "C" void kernel_launch(void* const* d_in, const int* in_sizes, int n_in,
                              void* d_out, int out_size, void* d_ws, size_t ws_size,
                              hipStream_t stream) {
  const float* scores = (const float*)d_in[0];
  const float* weight = (const float*)d_in[1];
  const float* bias   = (const float*)d_in[2];
  float* outp = (float*)d_out;
  u64* qprobs = (u64*)d_ws;   // B*G*L*L u64 quads = 256 MB (+ A-table hole)

  pack_w_k<<<1, 256, 0, stream>>>(weight, qprobs);

  softmax_q_k<<<B_SZ * N_G * L_DIM, 256, 0, stream>>>(scores, qprobs);

  conv_k<<<(L_DIM / BX) * (L_DIM / BY) * B_SZ * N_G, 256, 0, stream>>>(
      qprobs, bias, outp);
}